// Round 2
// baseline (140.269 us; speedup 1.0000x reference)
//
#include <hip/hip_runtime.h>
#include <hip/hip_bf16.h>

typedef __attribute__((ext_vector_type(8))) short bf16x8;
typedef __attribute__((ext_vector_type(4))) float f32x4;

__device__ __forceinline__ unsigned short f2bf(float f) {
  unsigned int u = __builtin_bit_cast(unsigned int, f);
  u += 0x7fffu + ((u >> 16) & 1u);
  return (unsigned short)(u >> 16);
}

__device__ __forceinline__ f32x4 mfma16(bf16x8 a, bf16x8 b, f32x4 c) {
  return __builtin_amdgcn_mfma_f32_16x16x32_bf16(a, b, c, 0, 0, 0);
}

// ---------------- K0: weight prep (fp32 -> bf16, padded) ----------------
// ws layout (unsigned short elements):
//   w1b [256][704]  (k 676..703 zero)
//   w2b [128][256]
//   w3b [64][128]
//   w4b [16][64]    (rows 10..15 zero)
__global__ void prep_weights(const float* __restrict__ w1, const float* __restrict__ w2,
                             const float* __restrict__ w3, const float* __restrict__ w4,
                             unsigned short* __restrict__ w1b, unsigned short* __restrict__ w2b,
                             unsigned short* __restrict__ w3b, unsigned short* __restrict__ w4b) {
  const int idx = blockIdx.x * blockDim.x + threadIdx.x;
  const int stride = gridDim.x * blockDim.x;
  for (int i = idx; i < 256 * 704; i += stride) {
    int o = i / 704, k = i - o * 704;
    w1b[i] = f2bf(k < 676 ? w1[o * 676 + k] : 0.f);
  }
  for (int i = idx; i < 128 * 256; i += stride) w2b[i] = f2bf(w2[i]);
  for (int i = idx; i < 64 * 128; i += stride) w3b[i] = f2bf(w3[i]);
  for (int i = idx; i < 16 * 64; i += stride) {
    int o = i >> 6, k = i & 63;
    w4b[i] = f2bf(o < 10 ? w4[o * 64 + k] : 0.f);
  }
}

// ---------------- K1: fused conv + 4-layer MLP ----------------
// Block: 256 threads (4 waves), BM=32 batch rows. Grid: 512 blocks (2/CU).
// B-operands (weights) are read DIRECTLY from global (L2-resident, 64B/row
// coalesced fragments) -> no LDS staging, no barriers inside any k-loop.
// LDS (static, 45,568 B -> 2 blocks/CU by grid; regions overlay):
//   hbT [32][712]  shorts 0..22783          (conv out, GEMM1 A)
//   h1s [32][264]  shorts 0..8447  (overlays hbT after barrier)
//   h2s [32][136]  shorts 8448..12799
//   h3s [32][72]   shorts 12800..15103
__global__ __launch_bounds__(256, 2) void fused_mlp(
    const float* __restrict__ x,             // [16384][784]
    const float* __restrict__ cw,            // [9]
    const unsigned short* __restrict__ w1b,  // [256][704]
    const unsigned short* __restrict__ w2b,  // [128][256]
    const unsigned short* __restrict__ w3b,  // [64][128]
    const unsigned short* __restrict__ w4b,  // [16][64]
    const float* __restrict__ b1, const float* __restrict__ b2,
    const float* __restrict__ b3, const float* __restrict__ b4,
    float* __restrict__ out)                 // [16384][10]
{
  __shared__ unsigned short lds_s[22784];
  unsigned short* hbT = lds_s;            // stride 712
  unsigned short* h1s = lds_s;            // stride 264 (overlays hbT)
  unsigned short* h2s = lds_s + 8448;     // stride 136
  unsigned short* h3s = lds_s + 12800;    // stride 72

  const int tid = threadIdx.x;
  const int lane = tid & 63;
  const int lane15 = lane & 15;
  const int kg = (lane >> 4) << 3;        // k sub-offset (0,8,16,24)
  const int w = tid >> 6;                 // wave 0..3
  const int row0 = blockIdx.x * 32;
  const int rb = (lane >> 4) << 2;        // C/D row base within 16x16 tile

  // ---- Phase 0: conv (3x3 VALID) -> hbT bf16 [32][704(+pad)] ----
  {
    const float c0 = cw[0], c1 = cw[1], c2 = cw[2];
    const float c3 = cw[3], c4 = cw[4], c5 = cw[5];
    const float c6 = cw[6], c7 = cw[7], c8 = cw[8];
    const float* xblk = x + (size_t)row0 * 784;
    for (int f = tid; f < 32 * 182; f += 256) {
      int rr = f / 182;
      int t = f - rr * 182;
      int i = t / 7;
      int jq = t - i * 7;
      int j0 = jq << 2;
      const float* xr = xblk + rr * 784 + i * 28 + j0;
      if (jq < 6) {
        float4 v00 = *(const float4*)(xr);
        float4 v01 = *(const float4*)(xr + 4);
        float4 v10 = *(const float4*)(xr + 28);
        float4 v11 = *(const float4*)(xr + 32);
        float4 v20 = *(const float4*)(xr + 56);
        float4 v21 = *(const float4*)(xr + 60);
        float r0[8] = {v00.x, v00.y, v00.z, v00.w, v01.x, v01.y, v01.z, v01.w};
        float r1[8] = {v10.x, v10.y, v10.z, v10.w, v11.x, v11.y, v11.z, v11.w};
        float r2[8] = {v20.x, v20.y, v20.z, v20.w, v21.x, v21.y, v21.z, v21.w};
        float o[4];
#pragma unroll
        for (int tt = 0; tt < 4; ++tt) {
          o[tt] = c0 * r0[tt] + c1 * r0[tt + 1] + c2 * r0[tt + 2]
                + c3 * r1[tt] + c4 * r1[tt + 1] + c5 * r1[tt + 2]
                + c6 * r2[tt] + c7 * r2[tt + 1] + c8 * r2[tt + 2];
        }
        unsigned int p0 = (unsigned)f2bf(o[0]) | ((unsigned)f2bf(o[1]) << 16);
        unsigned int p1 = (unsigned)f2bf(o[2]) | ((unsigned)f2bf(o[3]) << 16);
        unsigned int* dst = (unsigned int*)(hbT + rr * 712 + i * 26 + j0);
        dst[0] = p0;
        dst[1] = p1;
      } else {  // j0 == 24: outputs j=24,25 only
        float4 v0 = *(const float4*)(xr);
        float4 v1 = *(const float4*)(xr + 28);
        float4 v2 = *(const float4*)(xr + 56);
        float o0 = c0 * v0.x + c1 * v0.y + c2 * v0.z
                 + c3 * v1.x + c4 * v1.y + c5 * v1.z
                 + c6 * v2.x + c7 * v2.y + c8 * v2.z;
        float o1 = c0 * v0.y + c1 * v0.z + c2 * v0.w
                 + c3 * v1.y + c4 * v1.z + c5 * v1.w
                 + c6 * v2.y + c7 * v2.z + c8 * v2.w;
        unsigned int p0 = (unsigned)f2bf(o0) | ((unsigned)f2bf(o1) << 16);
        *(unsigned int*)(hbT + rr * 712 + i * 26 + 24) = p0;
      }
    }
    // zero-pad k = 676..703 (14 uints per row)
    for (int f = tid; f < 32 * 14; f += 256) {
      int rr = f / 14, u = f - rr * 14;
      *(unsigned int*)(hbT + rr * 712 + 676 + (u << 1)) = 0u;
    }
  }

  __syncthreads();

  // ---- GEMM1: [32][704] x w1^T -> [32][256]; wave w owns cols w*64..+63 ----
  // A from LDS (no barrier needed: read-only), B straight from global (L2).
  f32x4 acc1[2][4] = {};
  {
    const unsigned short* a0p = hbT + lane15 * 712 + kg;
    const unsigned short* a1p = hbT + (16 + lane15) * 712 + kg;
    const unsigned short* bp = w1b + (w * 64 + lane15) * 704 + kg;
#pragma unroll 2
    for (int ks = 0; ks < 22; ++ks) {
      const int k0 = ks << 5;
      bf16x8 a0 = *(const bf16x8*)(a0p + k0);
      bf16x8 a1 = *(const bf16x8*)(a1p + k0);
      bf16x8 fb0 = *(const bf16x8*)(bp + k0);
      bf16x8 fb1 = *(const bf16x8*)(bp + 16 * 704 + k0);
      bf16x8 fb2 = *(const bf16x8*)(bp + 32 * 704 + k0);
      bf16x8 fb3 = *(const bf16x8*)(bp + 48 * 704 + k0);
      acc1[0][0] = mfma16(a0, fb0, acc1[0][0]);
      acc1[1][0] = mfma16(a1, fb0, acc1[1][0]);
      acc1[0][1] = mfma16(a0, fb1, acc1[0][1]);
      acc1[1][1] = mfma16(a1, fb1, acc1[1][1]);
      acc1[0][2] = mfma16(a0, fb2, acc1[0][2]);
      acc1[1][2] = mfma16(a1, fb2, acc1[1][2]);
      acc1[0][3] = mfma16(a0, fb3, acc1[0][3]);
      acc1[1][3] = mfma16(a1, fb3, acc1[1][3]);
    }
  }

  __syncthreads();  // all hbT reads done before h1s overlays it

  // ---- epilogue1: +b1, relu, bf16 -> h1s [32][264] ----
#pragma unroll
  for (int n = 0; n < 4; ++n) {
    const int col = w * 64 + n * 16 + lane15;
    const float bias = b1[col];
#pragma unroll
    for (int m = 0; m < 2; ++m) {
#pragma unroll
      for (int r = 0; r < 4; ++r) {
        float v = acc1[m][n][r] + bias;
        v = v > 0.f ? v : 0.f;
        h1s[(rb + m * 16 + r) * 264 + col] = f2bf(v);
      }
    }
  }
  __syncthreads();

  // ---- GEMM2: [32][256] x w2^T -> [32][128]; wave w owns cols w*32..+31 ----
  f32x4 acc2[2][2] = {};
  {
    const unsigned short* a0p = h1s + lane15 * 264 + kg;
    const unsigned short* a1p = h1s + (16 + lane15) * 264 + kg;
    const unsigned short* bp = w2b + (w * 32 + lane15) * 256 + kg;
#pragma unroll
    for (int ks = 0; ks < 8; ++ks) {
      const int k0 = ks << 5;
      bf16x8 a0 = *(const bf16x8*)(a0p + k0);
      bf16x8 a1 = *(const bf16x8*)(a1p + k0);
      bf16x8 fb0 = *(const bf16x8*)(bp + k0);
      bf16x8 fb1 = *(const bf16x8*)(bp + 16 * 256 + k0);
      acc2[0][0] = mfma16(a0, fb0, acc2[0][0]);
      acc2[1][0] = mfma16(a1, fb0, acc2[1][0]);
      acc2[0][1] = mfma16(a0, fb1, acc2[0][1]);
      acc2[1][1] = mfma16(a1, fb1, acc2[1][1]);
    }
  }
  // epilogue2 -> h2s (disjoint region; no pre-barrier needed)
#pragma unroll
  for (int n = 0; n < 2; ++n) {
    const int col = w * 32 + n * 16 + lane15;
    const float bias = b2[col];
#pragma unroll
    for (int m = 0; m < 2; ++m) {
#pragma unroll
      for (int r = 0; r < 4; ++r) {
        float v = acc2[m][n][r] + bias;
        v = v > 0.f ? v : 0.f;
        h2s[(rb + m * 16 + r) * 136 + col] = f2bf(v);
      }
    }
  }
  __syncthreads();

  // ---- GEMM3: [32][128] x w3^T -> [32][64]; wave w owns cols w*16..+15 ----
  f32x4 acc3[2] = {};
  {
    const unsigned short* a0p = h2s + lane15 * 136 + kg;
    const unsigned short* a1p = h2s + (16 + lane15) * 136 + kg;
    const unsigned short* bp = w3b + (w * 16 + lane15) * 128 + kg;
#pragma unroll
    for (int ks = 0; ks < 4; ++ks) {
      const int k0 = ks << 5;
      bf16x8 a0 = *(const bf16x8*)(a0p + k0);
      bf16x8 a1 = *(const bf16x8*)(a1p + k0);
      bf16x8 fb0 = *(const bf16x8*)(bp + k0);
      acc3[0] = mfma16(a0, fb0, acc3[0]);
      acc3[1] = mfma16(a1, fb0, acc3[1]);
    }
  }
  // epilogue3 -> h3s (disjoint region)
  {
    const int col = w * 16 + lane15;
    const float bias = b3[col];
#pragma unroll
    for (int m = 0; m < 2; ++m) {
#pragma unroll
      for (int r = 0; r < 4; ++r) {
        float v = acc3[m][r] + bias;
        v = v > 0.f ? v : 0.f;
        h3s[(rb + m * 16 + r) * 72 + col] = f2bf(v);
      }
    }
  }
  __syncthreads();

  // ---- GEMM4: [32][64] x w4^T -> [32][10]; waves 0,1 take M-tiles 0,1 ----
  if (w < 2) {
    f32x4 acc4 = {};
    const unsigned short* ap = h3s + (w * 16 + lane15) * 72 + kg;
    const unsigned short* bp = w4b + lane15 * 64 + kg;
#pragma unroll
    for (int ks = 0; ks < 2; ++ks) {
      const int k0 = ks << 5;
      bf16x8 a0 = *(const bf16x8*)(ap + k0);
      bf16x8 fb0 = *(const bf16x8*)(bp + k0);
      acc4 = mfma16(a0, fb0, acc4);
    }
    const int col = lane15;
    if (col < 10) {
      const float bias = b4[col];
#pragma unroll
      for (int r = 0; r < 4; ++r) {
        out[(size_t)(row0 + w * 16 + rb + r) * 10 + col] = acc4[r] + bias;
      }
    }
  }
}

extern "C" void kernel_launch(void* const* d_in, const int* in_sizes, int n_in,
                              void* d_out, int out_size, void* d_ws, size_t ws_size,
                              hipStream_t stream) {
  const float* x  = (const float*)d_in[0];
  const float* cw = (const float*)d_in[1];
  const float* w1 = (const float*)d_in[2];
  const float* b1 = (const float*)d_in[3];
  const float* w2 = (const float*)d_in[4];
  const float* b2 = (const float*)d_in[5];
  const float* w3 = (const float*)d_in[6];
  const float* b3 = (const float*)d_in[7];
  const float* w4 = (const float*)d_in[8];
  const float* b4 = (const float*)d_in[9];
  float* out = (float*)d_out;

  unsigned short* w1b = (unsigned short*)d_ws;          // 256*704
  unsigned short* w2b = w1b + 256 * 704;                // 128*256
  unsigned short* w3b = w2b + 128 * 256;                // 64*128
  unsigned short* w4b = w3b + 64 * 128;                 // 16*64

  hipLaunchKernelGGL(prep_weights, dim3(256), dim3(256), 0, stream,
                     w1, w2, w3, w4, w1b, w2b, w3b, w4b);

  hipLaunchKernelGGL(fused_mlp, dim3(512), dim3(256), 0, stream,
                     x, cw, w1b, w2b, w3b, w4b, b1, b2, b3, b4, out);
}

// Round 4
// 125.169 us; speedup vs baseline: 1.1206x; 1.1206x over previous
//
#include <hip/hip_runtime.h>
#include <hip/hip_bf16.h>

typedef __attribute__((ext_vector_type(8))) short bf16x8;
typedef __attribute__((ext_vector_type(4))) float f32x4;

__device__ __forceinline__ unsigned short f2bf(float f) {
  unsigned int u = __builtin_bit_cast(unsigned int, f);
  u += 0x7fffu + ((u >> 16) & 1u);
  return (unsigned short)(u >> 16);
}

__device__ __forceinline__ f32x4 mfma16(bf16x8 a, bf16x8 b, f32x4 c) {
  return __builtin_amdgcn_mfma_f32_16x16x32_bf16(a, b, c, 0, 0, 0);
}

// ---------------- K0: weight prep ----------------
// Folds the 3x3 VALID conv into W1:  h@W1^T == x@(W1*C)^T, so
//   w1p[o, 28u+v] = sum_{a,b in [0,3): 0<=u-a<26, 0<=v-b<26} cw[a,b]*w1[o, 26*(u-a)+(v-b)]
// ws layout (unsigned short elems):
//   w1p [256][800]  (cols 784..799 zero)
//   w2b [128][256]
//   w3b [64][128]
//   w4b [16][64]    (rows 10..15 zero)
__global__ void prep_weights(const float* __restrict__ w1, const float* __restrict__ w2,
                             const float* __restrict__ w3, const float* __restrict__ w4,
                             const float* __restrict__ cw,
                             unsigned short* __restrict__ w1p, unsigned short* __restrict__ w2b,
                             unsigned short* __restrict__ w3b, unsigned short* __restrict__ w4b) {
  const int idx = blockIdx.x * blockDim.x + threadIdx.x;
  const int stride = gridDim.x * blockDim.x;
  for (int i = idx; i < 256 * 800; i += stride) {
    int o = i / 800, p = i - o * 800;
    float acc = 0.f;
    if (p < 784) {
      int u = p / 28, v = p - u * 28;
#pragma unroll
      for (int a = 0; a < 3; ++a) {
#pragma unroll
        for (int b = 0; b < 3; ++b) {
          int ii = u - a, jj = v - b;
          if (ii >= 0 && ii < 26 && jj >= 0 && jj < 26)
            acc += cw[a * 3 + b] * w1[o * 676 + 26 * ii + jj];
        }
      }
    }
    w1p[i] = f2bf(acc);
  }
  for (int i = idx; i < 128 * 256; i += stride) w2b[i] = f2bf(w2[i]);
  for (int i = idx; i < 64 * 128; i += stride) w3b[i] = f2bf(w3[i]);
  for (int i = idx; i < 16 * 64; i += stride) {
    int o = i >> 6, k = i & 63;
    w4b[i] = f2bf(o < 10 ? w4[o * 64 + k] : 0.f);
  }
}

// ---------------- K1: fused (cast x) + 4-layer MLP ----------------
// 512 threads (8 waves), BM=32 rows, grid 512 (2 blocks/CU -> 16 waves/CU).
// Weights read directly from global (L2-resident), 2-deep register prefetch
// in GEMM1. No barriers inside any k-loop; 5 barriers total.
// LDS (static 51,712 B; regions overlay):
//   xs  [32][808] shorts 0..25855   (bf16 x-tile; stride 808 -> 2-way banks, 16B-aligned rows)
//   h1s [32][264] @0      (overlays xs after GEMM1)
//   h2s [32][136] @12800
//   h3s [32][72]  @20480
__global__ __launch_bounds__(512, 4) void fused_mlp(
    const float* __restrict__ x,             // [16384][784]
    const unsigned short* __restrict__ w1p,  // [256][800]
    const unsigned short* __restrict__ w2b,  // [128][256]
    const unsigned short* __restrict__ w3b,  // [64][128]
    const unsigned short* __restrict__ w4b,  // [16][64]
    const float* __restrict__ b1, const float* __restrict__ b2,
    const float* __restrict__ b3, const float* __restrict__ b4,
    float* __restrict__ out)                 // [16384][10]
{
  __shared__ unsigned short lds_s[25856];
  unsigned short* xs  = lds_s;            // stride 808
  unsigned short* h1s = lds_s;            // stride 264
  unsigned short* h2s = lds_s + 12800;    // stride 136
  unsigned short* h3s = lds_s + 20480;    // stride 72

  const int tid = threadIdx.x;
  const int lane = tid & 63;
  const int lane15 = lane & 15;
  const int kg = (lane >> 4) << 3;        // k sub-offset in shorts (0,8,16,24)
  const int w = tid >> 6;                 // wave 0..7
  const int row0 = blockIdx.x * 32;
  const int rb = (lane >> 4) << 2;        // C/D row base within 16x16 tile

  // ---- Phase 0: x fp32 -> bf16 into xs ----
  {
    const float* xblk = x + (size_t)row0 * 784;
    for (int f = tid; f < 32 * 196; f += 512) {
      int rr = f / 196, c4 = f - rr * 196;
      float4 v = *(const float4*)(xblk + rr * 784 + (c4 << 2));
      unsigned int p0 = (unsigned)f2bf(v.x) | ((unsigned)f2bf(v.y) << 16);
      unsigned int p1 = (unsigned)f2bf(v.z) | ((unsigned)f2bf(v.w) << 16);
      unsigned int* dst = (unsigned int*)(xs + rr * 808 + (c4 << 2));
      dst[0] = p0;
      dst[1] = p1;
    }
    if (tid < 256) {  // zero-pad k = 784..799 (8 uints per row)
      int rr = tid >> 3, u = tid & 7;
      *(unsigned int*)(xs + rr * 808 + 784 + (u << 1)) = 0u;
    }
  }
  __syncthreads();

  // ---- GEMM1: [32][800] x w1p^T -> [32][256]; wave w owns cols w*32..+31 ----
  f32x4 acc1[2][2] = {};
  {
    const unsigned short* a0p = xs + lane15 * 808 + kg;
    const unsigned short* a1p = xs + (16 + lane15) * 808 + kg;
    const unsigned short* bp = w1p + (w * 32 + lane15) * 800 + kg;
    bf16x8 b0a = *(const bf16x8*)(bp);
    bf16x8 b1a = *(const bf16x8*)(bp + 16 * 800);
    bf16x8 b0b = *(const bf16x8*)(bp + 32);
    bf16x8 b1b = *(const bf16x8*)(bp + 16 * 800 + 32);
#pragma unroll
    for (int ks = 0; ks < 25; ++ks) {
      bf16x8 u0 = b0a, u1 = b1a;
      b0a = b0b; b1a = b1b;
      if (ks + 2 < 25) {
        b0b = *(const bf16x8*)(bp + (ks + 2) * 32);
        b1b = *(const bf16x8*)(bp + 16 * 800 + (ks + 2) * 32);
      }
      bf16x8 a0 = *(const bf16x8*)(a0p + ks * 32);
      bf16x8 a1 = *(const bf16x8*)(a1p + ks * 32);
      acc1[0][0] = mfma16(a0, u0, acc1[0][0]);
      acc1[1][0] = mfma16(a1, u0, acc1[1][0]);
      acc1[0][1] = mfma16(a0, u1, acc1[0][1]);
      acc1[1][1] = mfma16(a1, u1, acc1[1][1]);
    }
  }
  __syncthreads();  // all xs reads done before h1s overlays it

  // ---- epilogue1: +b1, relu -> h1s [32][264] ----
#pragma unroll
  for (int n = 0; n < 2; ++n) {
    const int col = w * 32 + n * 16 + lane15;
    const float bias = b1[col];
#pragma unroll
    for (int m = 0; m < 2; ++m) {
#pragma unroll
      for (int r = 0; r < 4; ++r) {
        float v = acc1[m][n][r] + bias;
        v = v > 0.f ? v : 0.f;
        h1s[(rb + m * 16 + r) * 264 + col] = f2bf(v);
      }
    }
  }
  __syncthreads();

  // ---- GEMM2: [32][256] x w2^T -> [32][128]; wave w owns cols w*16..+15 ----
  f32x4 acc2[2] = {};
  {
    const unsigned short* a0p = h1s + lane15 * 264 + kg;
    const unsigned short* a1p = h1s + (16 + lane15) * 264 + kg;
    const unsigned short* bp = w2b + (w * 16 + lane15) * 256 + kg;
#pragma unroll
    for (int ks = 0; ks < 8; ++ks) {
      const int k0 = ks << 5;
      bf16x8 a0 = *(const bf16x8*)(a0p + k0);
      bf16x8 a1 = *(const bf16x8*)(a1p + k0);
      bf16x8 fb = *(const bf16x8*)(bp + k0);
      acc2[0] = mfma16(a0, fb, acc2[0]);
      acc2[1] = mfma16(a1, fb, acc2[1]);
    }
  }
  // epilogue2 -> h2s (disjoint region)
  {
    const int col = w * 16 + lane15;
    const float bias = b2[col];
#pragma unroll
    for (int m = 0; m < 2; ++m) {
#pragma unroll
      for (int r = 0; r < 4; ++r) {
        float v = acc2[m][r] + bias;
        v = v > 0.f ? v : 0.f;
        h2s[(rb + m * 16 + r) * 136 + col] = f2bf(v);
      }
    }
  }
  __syncthreads();

  // ---- GEMM3: [32][128] x w3^T -> [32][64]; wave (mh=w>>2, cq=w&3) ----
  f32x4 acc3 = {};
  {
    const int mh = w >> 2, cq = w & 3;
    const unsigned short* ap = h2s + (mh * 16 + lane15) * 136 + kg;
    const unsigned short* bp = w3b + (cq * 16 + lane15) * 128 + kg;
#pragma unroll
    for (int ks = 0; ks < 4; ++ks) {
      const int k0 = ks << 5;
      bf16x8 a0 = *(const bf16x8*)(ap + k0);
      bf16x8 fb = *(const bf16x8*)(bp + k0);
      acc3 = mfma16(a0, fb, acc3);
    }
    // epilogue3 -> h3s (disjoint region)
    const int col = cq * 16 + lane15;
    const float bias = b3[col];
#pragma unroll
    for (int r = 0; r < 4; ++r) {
      float v = acc3[r] + bias;
      v = v > 0.f ? v : 0.f;
      h3s[(mh * 16 + rb + r) * 72 + col] = f2bf(v);
    }
  }
  __syncthreads();

  // ---- GEMM4: [32][64] x w4^T -> [32][10]; waves 0,1 take M halves ----
  if (w < 2) {
    f32x4 acc4 = {};
    const unsigned short* ap = h3s + (w * 16 + lane15) * 72 + kg;
    const unsigned short* bp = w4b + lane15 * 64 + kg;
#pragma unroll
    for (int ks = 0; ks < 2; ++ks) {
      const int k0 = ks << 5;
      bf16x8 a0 = *(const bf16x8*)(ap + k0);
      bf16x8 fb = *(const bf16x8*)(bp + k0);
      acc4 = mfma16(a0, fb, acc4);
    }
    const int col = lane15;
    if (col < 10) {
      const float bias = b4[col];
#pragma unroll
      for (int r = 0; r < 4; ++r) {
        out[(size_t)(row0 + w * 16 + rb + r) * 10 + col] = acc4[r] + bias;
      }
    }
  }
}

extern "C" void kernel_launch(void* const* d_in, const int* in_sizes, int n_in,
                              void* d_out, int out_size, void* d_ws, size_t ws_size,
                              hipStream_t stream) {
  const float* x  = (const float*)d_in[0];
  const float* cw = (const float*)d_in[1];
  const float* w1 = (const float*)d_in[2];
  const float* b1 = (const float*)d_in[3];
  const float* w2 = (const float*)d_in[4];
  const float* b2 = (const float*)d_in[5];
  const float* w3 = (const float*)d_in[6];
  const float* b3 = (const float*)d_in[7];
  const float* w4 = (const float*)d_in[8];
  const float* b4 = (const float*)d_in[9];
  float* out = (float*)d_out;

  unsigned short* w1p = (unsigned short*)d_ws;          // 256*800
  unsigned short* w2b = w1p + 256 * 800;                // 128*256
  unsigned short* w3b = w2b + 128 * 256;                // 64*128
  unsigned short* w4b = w3b + 64 * 128;                 // 16*64

  hipLaunchKernelGGL(prep_weights, dim3(256), dim3(256), 0, stream,
                     w1, w2, w3, w4, cw, w1p, w2b, w3b, w4b);

  hipLaunchKernelGGL(fused_mlp, dim3(512), dim3(512), 0, stream,
                     x, w1p, w2b, w3b, w4b, b1, b2, b3, b4, out);
}

// Round 5
// 121.877 us; speedup vs baseline: 1.1509x; 1.0270x over previous
//
#include <hip/hip_runtime.h>
#include <hip/hip_bf16.h>

typedef __attribute__((ext_vector_type(8))) short bf16x8;
typedef __attribute__((ext_vector_type(4))) float f32x4;

__device__ __forceinline__ unsigned short f2bf(float f) {
  unsigned int u = __builtin_bit_cast(unsigned int, f);
  u += 0x7fffu + ((u >> 16) & 1u);
  return (unsigned short)(u >> 16);
}

__device__ __forceinline__ f32x4 mfma16(bf16x8 a, bf16x8 b, f32x4 c) {
  return __builtin_amdgcn_mfma_f32_16x16x32_bf16(a, b, c, 0, 0, 0);
}

// ---------------- K0: weight prep (v2: per-row LDS staging) ----------------
// Folds the 3x3 VALID conv into W1:  h@W1^T == x@(W1*C)^T:
//   w1p[o, 28u+v] = sum_{a,b: 0<=u-a<26, 0<=v-b<26} cw[a,b]*w1[o, 26*(u-a)+(v-b)]
// Block o (of 256) stages w1 row o in LDS, computes 800 folded cols.
// ws layout (unsigned short elems):
//   w1p [256][800] (cols 784..799 zero), w2b [128][256], w3b [64][128],
//   w4b [16][64] (rows 10..15 zero)
__global__ __launch_bounds__(256) void prep_weights(
    const float* __restrict__ w1, const float* __restrict__ w2,
    const float* __restrict__ w3, const float* __restrict__ w4,
    const float* __restrict__ cw,
    unsigned short* __restrict__ w1p, unsigned short* __restrict__ w2b,
    unsigned short* __restrict__ w3b, unsigned short* __restrict__ w4b) {
  __shared__ float wrow[676];
  __shared__ float cws[9];
  const int o = blockIdx.x;
  const int t = threadIdx.x;
  if (t < 9) cws[t] = cw[t];
  for (int i = t; i < 676; i += 256) wrow[i] = w1[o * 676 + i];
  __syncthreads();
#pragma unroll
  for (int it = 0; it < 4; ++it) {
    int p = t + it * 256;
    if (p < 800) {
      float acc = 0.f;
      if (p < 784) {
        int u = p / 28, v = p - u * 28;
#pragma unroll
        for (int a = 0; a < 3; ++a) {
          int ii = u - a;
          if (ii < 0 || ii >= 26) continue;
#pragma unroll
          for (int b = 0; b < 3; ++b) {
            int jj = v - b;
            if (jj < 0 || jj >= 26) continue;
            acc += cws[a * 3 + b] * wrow[26 * ii + jj];
          }
        }
      }
      w1p[o * 800 + p] = f2bf(acc);
    }
  }
  // small casts, grid-strided across all 256 blocks
  const int idx = o * 256 + t;
  const int stride = 256 * 256;
  for (int i = idx; i < 128 * 256; i += stride) w2b[i] = f2bf(w2[i]);
  for (int i = idx; i < 64 * 128; i += stride) w3b[i] = f2bf(w3[i]);
  for (int i = idx; i < 16 * 64; i += stride) {
    int oo = i >> 6, k = i & 63;
    w4b[i] = f2bf(oo < 10 ? w4[oo * 64 + k] : 0.f);
  }
}

// ---------------- K1: fused (cast x) + 4-layer MLP ----------------
// 512 threads (8 waves), BM=32 rows, grid 512 (2 blocks/CU -> 16 waves/CU).
// GEMM1 B-fragments prefetched depth-3 from global (L2), hoisted ABOVE the
// x-cast phase so their latency hides under P0. No barriers in any k-loop.
// LDS (static 51,712 B; regions overlay):
//   xs  [32][808]  (stride 808 -> 2-way banks = free, rows 16B-aligned)
//   h1s [32][264] @0 (overlays xs)   h2s [32][136] @12800   h3s [32][72] @20480
__global__ __launch_bounds__(512, 4) void fused_mlp(
    const float* __restrict__ x,             // [16384][784]
    const unsigned short* __restrict__ w1p,  // [256][800]
    const unsigned short* __restrict__ w2b,  // [128][256]
    const unsigned short* __restrict__ w3b,  // [64][128]
    const unsigned short* __restrict__ w4b,  // [16][64]
    const float* __restrict__ b1, const float* __restrict__ b2,
    const float* __restrict__ b3, const float* __restrict__ b4,
    float* __restrict__ out)                 // [16384][10]
{
  __shared__ unsigned short lds_s[25856];
  unsigned short* xs  = lds_s;            // stride 808
  unsigned short* h1s = lds_s;            // stride 264
  unsigned short* h2s = lds_s + 12800;    // stride 136
  unsigned short* h3s = lds_s + 20480;    // stride 72

  const int tid = threadIdx.x;
  const int lane = tid & 63;
  const int lane15 = lane & 15;
  const int kg = (lane >> 4) << 3;        // k sub-offset in shorts (0,8,16,24)
  const int w = tid >> 6;                 // wave 0..7
  const int row0 = blockIdx.x * 32;
  const int rb = (lane >> 4) << 2;        // C/D row base within 16x16 tile

  // ---- hoisted GEMM1 B prefetch (depth 3), independent of xs ----
  const unsigned short* bp = w1p + (w * 32 + lane15) * 800 + kg;
  bf16x8 b0a = *(const bf16x8*)(bp);
  bf16x8 b0b = *(const bf16x8*)(bp + 16 * 800);
  bf16x8 b1a = *(const bf16x8*)(bp + 32);
  bf16x8 b1b = *(const bf16x8*)(bp + 16 * 800 + 32);
  bf16x8 b2a = *(const bf16x8*)(bp + 64);
  bf16x8 b2b = *(const bf16x8*)(bp + 16 * 800 + 64);

  // ---- Phase 0: x fp32 -> bf16 into xs ----
  {
    const float* xblk = x + (size_t)row0 * 784;
    for (int f = tid; f < 32 * 196; f += 512) {
      int rr = f / 196, c4 = f - rr * 196;
      float4 v = *(const float4*)(xblk + rr * 784 + (c4 << 2));
      unsigned int p0 = (unsigned)f2bf(v.x) | ((unsigned)f2bf(v.y) << 16);
      unsigned int p1 = (unsigned)f2bf(v.z) | ((unsigned)f2bf(v.w) << 16);
      unsigned int* dst = (unsigned int*)(xs + rr * 808 + (c4 << 2));
      dst[0] = p0;
      dst[1] = p1;
    }
    if (tid < 256) {  // zero-pad k = 784..799 (8 uints per row)
      int rr = tid >> 3, u = tid & 7;
      *(unsigned int*)(xs + rr * 808 + 784 + (u << 1)) = 0u;
    }
  }
  __syncthreads();

  // ---- GEMM1: [32][800] x w1p^T -> [32][256]; wave w owns cols w*32..+31 ----
  f32x4 acc1[2][2] = {};
  {
    const unsigned short* a0p = xs + lane15 * 808 + kg;
    const unsigned short* a1p = xs + (16 + lane15) * 808 + kg;
#pragma unroll
    for (int ks = 0; ks < 25; ++ks) {
      bf16x8 u0 = b0a, u1 = b0b;
      b0a = b1a; b0b = b1b;
      b1a = b2a; b1b = b2b;
      if (ks + 3 < 25) {
        b2a = *(const bf16x8*)(bp + (ks + 3) * 32);
        b2b = *(const bf16x8*)(bp + 16 * 800 + (ks + 3) * 32);
      }
      bf16x8 a0 = *(const bf16x8*)(a0p + ks * 32);
      bf16x8 a1 = *(const bf16x8*)(a1p + ks * 32);
      acc1[0][0] = mfma16(a0, u0, acc1[0][0]);
      acc1[1][0] = mfma16(a1, u0, acc1[1][0]);
      acc1[0][1] = mfma16(a0, u1, acc1[0][1]);
      acc1[1][1] = mfma16(a1, u1, acc1[1][1]);
    }
  }
  __syncthreads();  // all xs reads done before h1s overlays it

  // ---- epilogue1: +b1, relu -> h1s [32][264] ----
#pragma unroll
  for (int n = 0; n < 2; ++n) {
    const int col = w * 32 + n * 16 + lane15;
    const float bias = b1[col];
#pragma unroll
    for (int m = 0; m < 2; ++m) {
#pragma unroll
      for (int r = 0; r < 4; ++r) {
        float v = acc1[m][n][r] + bias;
        v = v > 0.f ? v : 0.f;
        h1s[(rb + m * 16 + r) * 264 + col] = f2bf(v);
      }
    }
  }
  __syncthreads();

  // ---- GEMM2: [32][256] x w2^T -> [32][128]; wave w owns cols w*16..+15 ----
  f32x4 acc2[2] = {};
  {
    const unsigned short* a0p = h1s + lane15 * 264 + kg;
    const unsigned short* a1p = h1s + (16 + lane15) * 264 + kg;
    const unsigned short* bp2 = w2b + (w * 16 + lane15) * 256 + kg;
#pragma unroll
    for (int ks = 0; ks < 8; ++ks) {
      const int k0 = ks << 5;
      bf16x8 a0 = *(const bf16x8*)(a0p + k0);
      bf16x8 a1 = *(const bf16x8*)(a1p + k0);
      bf16x8 fb = *(const bf16x8*)(bp2 + k0);
      acc2[0] = mfma16(a0, fb, acc2[0]);
      acc2[1] = mfma16(a1, fb, acc2[1]);
    }
  }
  // epilogue2 -> h2s (disjoint region)
  {
    const int col = w * 16 + lane15;
    const float bias = b2[col];
#pragma unroll
    for (int m = 0; m < 2; ++m) {
#pragma unroll
      for (int r = 0; r < 4; ++r) {
        float v = acc2[m][r] + bias;
        v = v > 0.f ? v : 0.f;
        h2s[(rb + m * 16 + r) * 136 + col] = f2bf(v);
      }
    }
  }
  __syncthreads();

  // ---- GEMM3: [32][128] x w3^T -> [32][64]; wave (mh=w>>2, cq=w&3) ----
  f32x4 acc3 = {};
  {
    const int mh = w >> 2, cq = w & 3;
    const unsigned short* ap = h2s + (mh * 16 + lane15) * 136 + kg;
    const unsigned short* bp3 = w3b + (cq * 16 + lane15) * 128 + kg;
#pragma unroll
    for (int ks = 0; ks < 4; ++ks) {
      const int k0 = ks << 5;
      bf16x8 a0 = *(const bf16x8*)(ap + k0);
      bf16x8 fb = *(const bf16x8*)(bp3 + k0);
      acc3 = mfma16(a0, fb, acc3);
    }
    // epilogue3 -> h3s (disjoint region)
    const int col = cq * 16 + lane15;
    const float bias = b3[col];
#pragma unroll
    for (int r = 0; r < 4; ++r) {
      float v = acc3[r] + bias;
      v = v > 0.f ? v : 0.f;
      h3s[(mh * 16 + rb + r) * 72 + col] = f2bf(v);
    }
  }
  __syncthreads();

  // ---- GEMM4: [32][64] x w4^T -> [32][10]; waves 0,1 take M halves ----
  if (w < 2) {
    f32x4 acc4 = {};
    const unsigned short* ap = h3s + (w * 16 + lane15) * 72 + kg;
    const unsigned short* bp4 = w4b + lane15 * 64 + kg;
#pragma unroll
    for (int ks = 0; ks < 2; ++ks) {
      const int k0 = ks << 5;
      bf16x8 a0 = *(const bf16x8*)(ap + k0);
      bf16x8 fb = *(const bf16x8*)(bp4 + k0);
      acc4 = mfma16(a0, fb, acc4);
    }
    const int col = lane15;
    if (col < 10) {
      const float bias = b4[col];
#pragma unroll
      for (int r = 0; r < 4; ++r) {
        out[(size_t)(row0 + w * 16 + rb + r) * 10 + col] = acc4[r] + bias;
      }
    }
  }
}

extern "C" void kernel_launch(void* const* d_in, const int* in_sizes, int n_in,
                              void* d_out, int out_size, void* d_ws, size_t ws_size,
                              hipStream_t stream) {
  const float* x  = (const float*)d_in[0];
  const float* cw = (const float*)d_in[1];
  const float* w1 = (const float*)d_in[2];
  const float* b1 = (const float*)d_in[3];
  const float* w2 = (const float*)d_in[4];
  const float* b2 = (const float*)d_in[5];
  const float* w3 = (const float*)d_in[6];
  const float* b3 = (const float*)d_in[7];
  const float* w4 = (const float*)d_in[8];
  const float* b4 = (const float*)d_in[9];
  float* out = (float*)d_out;

  unsigned short* w1p = (unsigned short*)d_ws;          // 256*800
  unsigned short* w2b = w1p + 256 * 800;                // 128*256
  unsigned short* w3b = w2b + 128 * 256;                // 64*128
  unsigned short* w4b = w3b + 64 * 128;                 // 16*64

  hipLaunchKernelGGL(prep_weights, dim3(256), dim3(256), 0, stream,
                     w1, w2, w3, w4, cw, w1p, w2b, w3b, w4b);

  hipLaunchKernelGGL(fused_mlp, dim3(512), dim3(512), 0, stream,
                     x, w1p, w2b, w3b, w4b, b1, b2, b3, b4, out);
}